// Round 3
// baseline (512.768 us; speedup 1.0000x reference)
//
#include <hip/hip_runtime.h>

#define BB 1024
#define TT 512
#define KK 64
#define NEGV -10000.0f

typedef _Float16 h2 __attribute__((ext_vector_type(2)));

#if defined(__has_builtin)
#if __has_builtin(__builtin_amdgcn_fdot2)
#define HAVE_FDOT2 1
#endif
#endif

static __device__ __forceinline__ float dot2_acc(h2 a, h2 b, float c) {
#ifdef HAVE_FDOT2
    return __builtin_amdgcn_fdot2(a, b, c, false);
#else
    return fmaf((float)a.x, (float)b.x, fmaf((float)a.y, (float)b.y, c));
#endif
}

static __device__ __forceinline__ h2 bc_h2(float f) {
    return __builtin_bit_cast(h2, f);
}

// ---------------------------------------------------------------------------
// gold_kernel: gold_score[b] = sum_t trans[tag_t][tag_{t-1}] + feats[b,t,tag_t]
//              + trans[STOP][tag_{T-1}]
// ---------------------------------------------------------------------------
__global__ __launch_bounds__(256) void gold_kernel(const float* __restrict__ feats,
                                                   const int* __restrict__ tags,
                                                   const float* __restrict__ trans,
                                                   float* __restrict__ gold) {
    const int wv = threadIdx.x >> 6;
    const int lane = threadIdx.x & 63;
    const int b = blockIdx.x * 4 + wv;
    const int* tg = tags + (size_t)b * TT;
    float acc = 0.f;
#pragma unroll
    for (int i = 0; i < TT / 64; ++i) {
        int t = lane + i * 64;
        int nxt = tg[t];
        int prv = (t == 0) ? 0 : tg[t - 1];
        acc += trans[nxt * KK + prv] + feats[((size_t)b * TT + t) * KK + nxt];
    }
    if (lane == 0) acc += trans[(KK - 1) * KK + tg[TT - 1]];  // STOP term
#pragma unroll
    for (int d = 1; d < 64; d <<= 1) acc += __shfl_xor(acc, d);
    if (lane == 0) gold[b] = acc;
}

// ---------------------------------------------------------------------------
// crf_kernel<GBP>: one block (2 waves) per batch; wave roles independent,
// no barriers, no shared state between waves.
//   role 0: forward logsumexp (f16 broadcast + v_dot2, pipelined ref shfl)
//   role 1: Viterbi (exact fp32, deferred-epilogue pipeline, bp in global
//           [GBP=1] or LDS [fallback], shfl-chain backtrace)
// ---------------------------------------------------------------------------
template <bool GBP>
__global__ __launch_bounds__(128) void crf_kernel(const float* __restrict__ feats,
                                                  const float* __restrict__ trans,
                                                  const float* __restrict__ gold,
                                                  unsigned char* __restrict__ bp_g,
                                                  float* __restrict__ out) {
    __shared__ __align__(16) float wa_buf[KK];          // viterbi alpha broadcast
    __shared__ __align__(16) _Float16 ea_buf[KK];       // exp(alpha - ref), f16
    __shared__ unsigned char bp_l[GBP ? 4 : TT * KK];   // fallback backpointers

    const int b = blockIdx.x;
    const int wv = threadIdx.x >> 6;
    const int lane = threadIdx.x & 63;
    const int role = wv ^ (b & 1);   // spread roles across SIMDs

    const float* fb = feats + (size_t)b * TT * KK + lane;

    if (role == 0) {
        // ================= FORWARD WAVE =================
        h2 Er_pk[32];
        {
            const float4* trow = reinterpret_cast<const float4*>(trans + lane * KK);
#pragma unroll
            for (int i = 0; i < 16; ++i) {
                float4 v = trow[i];
                h2 lo, hi;
                lo.x = (_Float16)__expf(v.x); lo.y = (_Float16)__expf(v.y);
                hi.x = (_Float16)__expf(v.z); hi.y = (_Float16)__expf(v.w);
                Er_pk[2 * i] = lo;
                Er_pk[2 * i + 1] = hi;
            }
        }
        const float t63 = trans[(KK - 1) * KK + lane];  // trans[STOP][lane]

        float a = (lane == 0) ? 0.f : NEGV;
        // pipelined wave-uniform normalizer: refUse(t) = shfl(a_{t-2}) + 5
        float refUse = 0.f, refMid = 6.f, refNew = 12.f;

        // feats prefetch depth 2
        float f0 = fb[0];
        float f1 = fb[KK];
        const float* fp = fb + 2 * KK;

        for (int t = 0; t < TT; ++t) {
            const float f_cur = f0;
            f0 = f1;
            f1 = *fp;                             // row min(t+2, TT-1)
            if (t + 3 < TT) fp += KK;

            float x = fminf(a - refUse, 11.0f);   // e^11 < f16 max
            ea_buf[lane] = (_Float16)__expf(x);
            // single-wave user of ea_buf: in-order DS pipe, no barrier

            const float4* eb = reinterpret_cast<const float4*>(ea_buf);
            float s0 = 0.f, s1 = 0.f, s2 = 0.f, s3 = 0.f;
            float s4 = 0.f, s5 = 0.f, s6 = 0.f, s7 = 0.f;
#pragma unroll
            for (int q = 0; q < 8; ++q) {
                float4 e4 = eb[q];
                float acc = 0.f;
                acc = dot2_acc(bc_h2(e4.x), Er_pk[4 * q + 0], acc);
                acc = dot2_acc(bc_h2(e4.y), Er_pk[4 * q + 1], acc);
                acc = dot2_acc(bc_h2(e4.z), Er_pk[4 * q + 2], acc);
                acc = dot2_acc(bc_h2(e4.w), Er_pk[4 * q + 3], acc);
                switch (q) {   // 8 independent 4-deep chains
                    case 0: s0 = acc; break; case 1: s1 = acc; break;
                    case 2: s2 = acc; break; case 3: s3 = acc; break;
                    case 4: s4 = acc; break; case 5: s5 = acc; break;
                    case 6: s6 = acc; break; case 7: s7 = acc; break;
                }
            }
            float s = ((s0 + s1) + (s2 + s3)) + ((s4 + s5) + (s6 + s7));
            float a_new = __logf(s) + refUse + f_cur;
            refUse = refMid;
            refMid = refNew;
            refNew = __shfl(a_new, 8) + 5.0f;   // consumed 2 iterations later
            a = a_new;
        }

        // exact terminal logsumexp(alpha_T + trans[STOP][:])
        float v = a + t63;
        float mm = v;
#pragma unroll
        for (int d = 32; d; d >>= 1) mm = fmaxf(mm, __shfl_xor(mm, d));
        float es = __expf(v - mm);
#pragma unroll
        for (int d = 32; d; d >>= 1) es += __shfl_xor(es, d);
        float fscore = mm + __logf(es);
        if (lane == 0) out[b] = fscore - gold[b];
    } else {
        // ================= VITERBI WAVE =================
        float tr[KK];
        {
            const float4* trow = reinterpret_cast<const float4*>(trans + lane * KK);
#pragma unroll
            for (int i = 0; i < KK / 4; ++i) {
                float4 v = trow[i];
                tr[4 * i + 0] = v.x; tr[4 * i + 1] = v.y;
                tr[4 * i + 2] = v.z; tr[4 * i + 3] = v.w;
            }
        }
        const float t63 = trans[(KK - 1) * KK + lane];

        unsigned char* bpc = GBP ? (bp_g + (size_t)b * TT * KK + lane) : (bp_l + lane);

        float w = (lane == 0) ? 0.f : NEGV;
        wa_buf[lane] = w;

        float f0 = fb[0];
        float f1 = fb[KK];
        const float* fp = fb + 2 * KK;

        // pending (deferred) epilogue state for step t-1
        float4 p_wa0, p_wa1, p_tg0, p_tg1;
        float p_m = 0.f;
        int p_base = 0;
        unsigned char* bpw = bpc;   // store cursor (row t-1)

        for (int t = 0; t < TT; ++t) {
            // ---- finish step t-1's argmax + bp store (operands long in flight) ----
            if (t) {
                int bpv = p_base;
                float vv;
                vv = p_wa1.w + p_tg1.w; if (vv == p_m) bpv = p_base + 7;
                vv = p_wa1.z + p_tg1.z; if (vv == p_m) bpv = p_base + 6;
                vv = p_wa1.y + p_tg1.y; if (vv == p_m) bpv = p_base + 5;
                vv = p_wa1.x + p_tg1.x; if (vv == p_m) bpv = p_base + 4;
                vv = p_wa0.w + p_tg0.w; if (vv == p_m) bpv = p_base + 3;
                vv = p_wa0.z + p_tg0.z; if (vv == p_m) bpv = p_base + 2;
                vv = p_wa0.y + p_tg0.y; if (vv == p_m) bpv = p_base + 1;
                vv = p_wa0.x + p_tg0.x; if (vv == p_m) bpv = p_base + 0;
                *bpw = (unsigned char)bpv;   // posted store (global) / DS b8 (lds)
                bpw += KK;
            }

            const float f_cur = f0;
            f0 = f1;
            f1 = *fp;
            if (t + 3 < TT) fp += KK;

            float gm[8];
#pragma unroll
            for (int gi = 0; gi < 8; ++gi) gm[gi] = -3.4e38f;

            const float4* wb = reinterpret_cast<const float4*>(wa_buf);
#pragma unroll
            for (int q = 0; q < 16; ++q) {
                float4 w4 = wb[q];
                float v0 = w4.x + tr[4 * q + 0];
                float v1 = w4.y + tr[4 * q + 1];
                float v2 = w4.z + tr[4 * q + 2];
                float v3 = w4.w + tr[4 * q + 3];
                int g = q >> 1;
                gm[g] = fmaxf(fmaxf(gm[g], v0), v1);   // fuses to v_max3
                gm[g] = fmaxf(fmaxf(gm[g], v2), v3);
            }

            float m = fmaxf(fmaxf(fmaxf(gm[0], gm[1]), fmaxf(gm[2], gm[3])),
                            fmaxf(fmaxf(gm[4], gm[5]), fmaxf(gm[6], gm[7])));
            int g = 0;
#pragma unroll
            for (int j = 7; j >= 0; --j)   // descending: smallest matching group
                if (gm[j] == m) g = j;
            const int base = g * 8;

            // issue re-reads (consumed NEXT iteration), then publish w_new
            const float4* wam = reinterpret_cast<const float4*>(wa_buf + base);
            p_wa0 = wam[0];
            p_wa1 = wam[1];                     // DS reads before the write below
            wa_buf[lane] = m + f_cur;           // in-order DS pipe: reads see old
            const float4* trg = reinterpret_cast<const float4*>(trans + lane * KK + base);
            p_tg0 = trg[0];
            p_tg1 = trg[1];                     // global loads, full-step cover
            p_m = m;
            p_base = base;
            w = m + f_cur;
        }
        // finish last step's bp
        {
            int bpv = p_base;
            float vv;
            vv = p_wa1.w + p_tg1.w; if (vv == p_m) bpv = p_base + 7;
            vv = p_wa1.z + p_tg1.z; if (vv == p_m) bpv = p_base + 6;
            vv = p_wa1.y + p_tg1.y; if (vv == p_m) bpv = p_base + 5;
            vv = p_wa1.x + p_tg1.x; if (vv == p_m) bpv = p_base + 4;
            vv = p_wa0.w + p_tg0.w; if (vv == p_m) bpv = p_base + 3;
            vv = p_wa0.z + p_tg0.z; if (vv == p_m) bpv = p_base + 2;
            vv = p_wa0.y + p_tg0.y; if (vv == p_m) bpv = p_base + 1;
            vv = p_wa0.x + p_tg0.x; if (vv == p_m) bpv = p_base + 0;
            *bpw = (unsigned char)bpv;
        }

        // ---- terminal: max + first-index argmax (exact) ----
        float tv = w + t63;
        float bvv = tv;
        int bidx = lane;
#pragma unroll
        for (int d = 1; d < 64; d <<= 1) {
            float ov = __shfl_xor(bvv, d);
            int oi = __shfl_xor(bidx, d);
            bool take = (ov > bvv) || (ov == bvv && oi < bidx);
            bvv = take ? ov : bvv;
            bidx = take ? oi : bidx;
        }
        if (lane == 0) out[BB + b] = bvv;

        // ---- backtrace: bulk row loads + dynamic-shfl chain ----
        float* outp = out + 2 * BB + (size_t)b * TT;
        int cur = bidx;                 // uniform across lanes
        float my = 0.f;                 // latched path values (lane = t & 63)
        for (int tb = TT - 16; tb >= 0; tb -= 16) {
            int r[16];
#pragma unroll
            for (int j = 0; j < 16; ++j)
                r[j] = GBP ? (int)bpc[(size_t)(tb + j) * KK]
                           : (int)bp_l[(tb + j) * KK + lane];
#pragma unroll
            for (int j = 15; j >= 0; --j) {
                my = (lane == ((tb + j) & 63)) ? (float)cur : my;
                cur = __shfl(r[j], cur);   // cur stays wave-uniform
            }
            if ((tb & 63) == 0) outp[tb + lane] = my;   // coalesced 64-wide store
        }
    }
}

extern "C" void kernel_launch(void* const* d_in, const int* in_sizes, int n_in,
                              void* d_out, int out_size, void* d_ws, size_t ws_size,
                              hipStream_t stream) {
    const float* feats = (const float*)d_in[0];
    const int* tags = (const int*)d_in[1];
    const float* trans = (const float*)d_in[2];
    float* out = (float*)d_out;
    float* gold = (float*)d_ws;
    unsigned char* bp_g = (unsigned char*)d_ws + 4096;

    gold_kernel<<<BB / 4, 256, 0, stream>>>(feats, tags, trans, gold);

    const size_t need = (size_t)BB * TT * KK + 4096;
    if (ws_size >= need) {
        crf_kernel<true><<<BB, 128, 0, stream>>>(feats, trans, gold, bp_g, out);
    } else {
        crf_kernel<false><<<BB, 128, 0, stream>>>(feats, trans, gold, nullptr, out);
    }
}

// Round 4
// 358.431 us; speedup vs baseline: 1.4306x; 1.4306x over previous
//
#include <hip/hip_runtime.h>

#define BB 1024
#define TT 512
#define KK 64
#define NEGV -10000.0f

typedef _Float16 h2 __attribute__((ext_vector_type(2)));

#if defined(__has_builtin)
#if __has_builtin(__builtin_amdgcn_fdot2)
#define HAVE_FDOT2 1
#endif
#endif

static __device__ __forceinline__ float dot2_acc(h2 a, h2 b, float c) {
#ifdef HAVE_FDOT2
    return __builtin_amdgcn_fdot2(a, b, c, false);
#else
    return fmaf((float)a.x, (float)b.x, fmaf((float)a.y, (float)b.y, c));
#endif
}

static __device__ __forceinline__ h2 bc_h2(float f) {
    return __builtin_bit_cast(h2, f);
}

// ---------------------------------------------------------------------------
// gold_kernel: gold_score[b] = sum_t trans[tag_t][tag_{t-1}] + feats[b,t,tag_t]
//              + trans[STOP][tag_{T-1}]
// ---------------------------------------------------------------------------
__global__ __launch_bounds__(256) void gold_kernel(const float* __restrict__ feats,
                                                   const int* __restrict__ tags,
                                                   const float* __restrict__ trans,
                                                   float* __restrict__ gold) {
    const int wv = threadIdx.x >> 6;
    const int lane = threadIdx.x & 63;
    const int b = blockIdx.x * 4 + wv;
    const int* tg = tags + (size_t)b * TT;
    float acc = 0.f;
#pragma unroll
    for (int i = 0; i < TT / 64; ++i) {
        int t = lane + i * 64;
        int nxt = tg[t];
        int prv = (t == 0) ? 0 : tg[t - 1];
        acc += trans[nxt * KK + prv] + feats[((size_t)b * TT + t) * KK + nxt];
    }
    if (lane == 0) acc += trans[(KK - 1) * KK + tg[TT - 1]];  // STOP term
#pragma unroll
    for (int d = 1; d < 64; d <<= 1) acc += __shfl_xor(acc, d);
    if (lane == 0) gold[b] = acc;
}

// ---------------------------------------------------------------------------
// crf_kernel: one block (2 waves) per batch; waves fully independent
// (no barriers, no shared state). __launch_bounds__(128,1): full VGPR budget
// so tr[64] stays in registers (R3's 64-VGPR cap spilled it -> regression).
//   role 0: forward logsumexp (f16 broadcast + v_dot2, 2-deep pipelined ref)
//   role 1: Viterbi, exact fp32, DEFERRED epilogue (argmax operand loads for
//           step t consumed at step t+1 -> no exposed LDS/global latency),
//           bp in LDS, shfl-chain backtrace.
// ---------------------------------------------------------------------------
__global__ __launch_bounds__(128, 1) void crf_kernel(const float* __restrict__ feats,
                                                     const float* __restrict__ trans,
                                                     const float* __restrict__ gold,
                                                     float* __restrict__ out) {
    __shared__ unsigned char bp[TT][KK];            // 32 KB backpointers
    __shared__ __align__(16) float wa_buf[KK];      // viterbi alpha broadcast
    __shared__ __align__(16) _Float16 ea_buf[KK];   // exp(alpha - ref), f16

    const int b = blockIdx.x;
    const int wv = threadIdx.x >> 6;
    const int lane = threadIdx.x & 63;
    const int role = wv ^ (b & 1);   // spread roles across SIMDs

    const float* fb = feats + (size_t)b * TT * KK + lane;

    if (role == 0) {
        // ================= FORWARD WAVE =================
        h2 Er_pk[32];
        {
            const float4* trow = reinterpret_cast<const float4*>(trans + lane * KK);
#pragma unroll
            for (int i = 0; i < 16; ++i) {
                float4 v = trow[i];
                h2 lo, hi;
                lo.x = (_Float16)__expf(v.x); lo.y = (_Float16)__expf(v.y);
                hi.x = (_Float16)__expf(v.z); hi.y = (_Float16)__expf(v.w);
                Er_pk[2 * i] = lo;
                Er_pk[2 * i + 1] = hi;
            }
        }
        const float t63 = trans[(KK - 1) * KK + lane];  // trans[STOP][lane]

        float a = (lane == 0) ? 0.f : NEGV;
        // pipelined wave-uniform normalizer: refUse(t) = shfl(a_{t-2}, 8) + 5
        float refUse = 0.f, refMid = 6.f, refNew = 12.f;

        float f0 = fb[0];
        float f1 = fb[KK];
        const float* fp = fb + 2 * KK;

        for (int t = 0; t < TT; ++t) {
            const float f_cur = f0;
            f0 = f1;
            f1 = *fp;
            if (t + 3 < TT) fp += KK;

            float x = fminf(a - refUse, 11.0f);   // e^11 < f16 max
            ea_buf[lane] = (_Float16)__expf(x);
            // single-wave user of ea_buf: in-order DS pipe, no barrier

            const float4* eb = reinterpret_cast<const float4*>(ea_buf);
            float s0 = 0.f, s1 = 0.f, s2 = 0.f, s3 = 0.f;
            float s4 = 0.f, s5 = 0.f, s6 = 0.f, s7 = 0.f;
#pragma unroll
            for (int q = 0; q < 8; ++q) {
                float4 e4 = eb[q];
                float acc = 0.f;
                acc = dot2_acc(bc_h2(e4.x), Er_pk[4 * q + 0], acc);
                acc = dot2_acc(bc_h2(e4.y), Er_pk[4 * q + 1], acc);
                acc = dot2_acc(bc_h2(e4.z), Er_pk[4 * q + 2], acc);
                acc = dot2_acc(bc_h2(e4.w), Er_pk[4 * q + 3], acc);
                switch (q) {   // 8 independent chains
                    case 0: s0 = acc; break; case 1: s1 = acc; break;
                    case 2: s2 = acc; break; case 3: s3 = acc; break;
                    case 4: s4 = acc; break; case 5: s5 = acc; break;
                    case 6: s6 = acc; break; case 7: s7 = acc; break;
                }
            }
            float s = ((s0 + s1) + (s2 + s3)) + ((s4 + s5) + (s6 + s7));
            float a_new = __logf(s) + refUse + f_cur;
            refUse = refMid;
            refMid = refNew;
            refNew = __shfl(a_new, 8) + 5.0f;   // consumed 2 iterations later
            a = a_new;
        }

        // exact terminal logsumexp(alpha_T + trans[STOP][:])
        float v = a + t63;
        float mm = v;
#pragma unroll
        for (int d = 32; d; d >>= 1) mm = fmaxf(mm, __shfl_xor(mm, d));
        float es = __expf(v - mm);
#pragma unroll
        for (int d = 32; d; d >>= 1) es += __shfl_xor(es, d);
        float fscore = mm + __logf(es);
        if (lane == 0) out[b] = fscore - gold[b];
    } else {
        // ================= VITERBI WAVE =================
        float tr[KK];
        {
            const float4* trow = reinterpret_cast<const float4*>(trans + lane * KK);
#pragma unroll
            for (int i = 0; i < KK / 4; ++i) {
                float4 v = trow[i];
                tr[4 * i + 0] = v.x; tr[4 * i + 1] = v.y;
                tr[4 * i + 2] = v.z; tr[4 * i + 3] = v.w;
            }
        }
        const float t63 = trans[(KK - 1) * KK + lane];

        float w = (lane == 0) ? 0.f : NEGV;
        wa_buf[lane] = w;

        float f0 = fb[0];
        float f1 = fb[KK];
        const float* fp = fb + 2 * KK;

        // pending (deferred) epilogue state for step t-1
        float4 p_wa0 = {}, p_wa1 = {}, p_tg0 = {}, p_tg1 = {};
        float p_m = 0.f;
        int p_base = 0;

        for (int t = 0; t < TT; ++t) {
            // ---- finish step t-1: argmax compare + bp store (operands have a
            //      full iteration of latency cover) ----
            if (t) {
                int bpv = p_base;
                float vv;
                vv = p_wa1.w + p_tg1.w; if (vv == p_m) bpv = p_base + 7;
                vv = p_wa1.z + p_tg1.z; if (vv == p_m) bpv = p_base + 6;
                vv = p_wa1.y + p_tg1.y; if (vv == p_m) bpv = p_base + 5;
                vv = p_wa1.x + p_tg1.x; if (vv == p_m) bpv = p_base + 4;
                vv = p_wa0.w + p_tg0.w; if (vv == p_m) bpv = p_base + 3;
                vv = p_wa0.z + p_tg0.z; if (vv == p_m) bpv = p_base + 2;
                vv = p_wa0.y + p_tg0.y; if (vv == p_m) bpv = p_base + 1;
                vv = p_wa0.x + p_tg0.x; if (vv == p_m) bpv = p_base + 0;
                bp[t - 1][lane] = (unsigned char)bpv;
            }

            const float f_cur = f0;
            f0 = f1;
            f1 = *fp;
            if (t + 3 < TT) fp += KK;

            float gm[8];
#pragma unroll
            for (int gi = 0; gi < 8; ++gi) gm[gi] = -3.4e38f;

            const float4* wb = reinterpret_cast<const float4*>(wa_buf);
#pragma unroll
            for (int q = 0; q < 16; ++q) {
                float4 w4 = wb[q];
                float v0 = w4.x + tr[4 * q + 0];
                float v1 = w4.y + tr[4 * q + 1];
                float v2 = w4.z + tr[4 * q + 2];
                float v3 = w4.w + tr[4 * q + 3];
                int g = q >> 1;
                gm[g] = fmaxf(fmaxf(gm[g], v0), v1);   // fuses to v_max3
                gm[g] = fmaxf(fmaxf(gm[g], v2), v3);
            }

            float m = fmaxf(fmaxf(fmaxf(gm[0], gm[1]), fmaxf(gm[2], gm[3])),
                            fmaxf(fmaxf(gm[4], gm[5]), fmaxf(gm[6], gm[7])));
            int g = 0;
#pragma unroll
            for (int j = 7; j >= 0; --j)   // descending: smallest matching group
                if (gm[j] == m) g = j;
            const int base = g * 8;

            // issue deferred-epilogue loads (consumed next iteration)
            const float4* wam = reinterpret_cast<const float4*>(wa_buf + base);
            p_wa0 = wam[0];
            p_wa1 = wam[1];                     // DS reads BEFORE the write below
            wa_buf[lane] = m + f_cur;           // in-order DS pipe: reads see old
            const float4* trg = reinterpret_cast<const float4*>(trans + lane * KK + base);
            p_tg0 = trg[0];
            p_tg1 = trg[1];                     // global loads, full-step cover
            p_m = m;
            p_base = base;
            w = m + f_cur;
        }
        // finish last step's bp
        {
            int bpv = p_base;
            float vv;
            vv = p_wa1.w + p_tg1.w; if (vv == p_m) bpv = p_base + 7;
            vv = p_wa1.z + p_tg1.z; if (vv == p_m) bpv = p_base + 6;
            vv = p_wa1.y + p_tg1.y; if (vv == p_m) bpv = p_base + 5;
            vv = p_wa1.x + p_tg1.x; if (vv == p_m) bpv = p_base + 4;
            vv = p_wa0.w + p_tg0.w; if (vv == p_m) bpv = p_base + 3;
            vv = p_wa0.z + p_tg0.z; if (vv == p_m) bpv = p_base + 2;
            vv = p_wa0.y + p_tg0.y; if (vv == p_m) bpv = p_base + 1;
            vv = p_wa0.x + p_tg0.x; if (vv == p_m) bpv = p_base + 0;
            bp[TT - 1][lane] = (unsigned char)bpv;
        }

        // ---- terminal: max + first-index argmax (exact) ----
        float tv = w + t63;
        float bvv = tv;
        int bidx = lane;
#pragma unroll
        for (int d = 1; d < 64; d <<= 1) {
            float ov = __shfl_xor(bvv, d);
            int oi = __shfl_xor(bidx, d);
            bool take = (ov > bvv) || (ov == bvv && oi < bidx);
            bvv = take ? ov : bvv;
            bidx = take ? oi : bidx;
        }
        if (lane == 0) out[BB + b] = bvv;

        // ---- backtrace: bulk LDS row loads + dynamic-shfl chain ----
        float* outp = out + 2 * BB + (size_t)b * TT;
        int cur = bidx;                 // wave-uniform
        float my = 0.f;                 // latched path values (lane = t & 63)
        for (int tb = TT - 16; tb >= 0; tb -= 16) {
            int r[16];
#pragma unroll
            for (int j = 0; j < 16; ++j) r[j] = bp[tb + j][lane];
#pragma unroll
            for (int j = 15; j >= 0; --j) {
                my = (lane == ((tb + j) & 63)) ? (float)cur : my;
                cur = __shfl(r[j], cur);
            }
            if ((tb & 63) == 0) outp[tb + lane] = my;   // coalesced 64-wide store
        }
    }
}

extern "C" void kernel_launch(void* const* d_in, const int* in_sizes, int n_in,
                              void* d_out, int out_size, void* d_ws, size_t ws_size,
                              hipStream_t stream) {
    const float* feats = (const float*)d_in[0];
    const int* tags = (const int*)d_in[1];
    const float* trans = (const float*)d_in[2];
    float* out = (float*)d_out;
    float* gold = (float*)d_ws;

    gold_kernel<<<BB / 4, 256, 0, stream>>>(feats, tags, trans, gold);
    crf_kernel<<<BB, 128, 0, stream>>>(feats, trans, gold, out);
}